// Round 5
// baseline (223.163 us; speedup 1.0000x reference)
//
#include <hip/hip_runtime.h>
#include <cstdint>
#include <cstddef>

// Problem constants (fixed by the reference)
#define B_      32
#define N_      8400
#define C_      80
#define NC      672000        // N_*C_
#define NCV4    168000        // NC/4
#define NBINS   4096
#define TOPK    1024
#define MAXDET  300
#define CANDCAP 4096
#define NSLICE  16
#define SLICE_V4 10500        // NCV4 / NSLICE
#define SEGCAP  256           // per-(batch,slice) key segment (expect ~82, 19 sigma)

// Static stage threshold: score >= 4088/4096 = 0.998046875.
// Expected candidates/batch = 672000*8/4096 = 1312 (sd ~36): inside
// [TOPK, CANDCAP] with overwhelming margin on the uniform bench input.
// Any violating input takes the exact histogram fallback in mega_kernel.
#define STAGE_THRESH 0.998046875f

// Workspace layout (bytes)
#define WS_CANDKEYS  0              // 32*4096*8 = 1048576 (16 segments of 256/batch)
#define WS_SEGCNT    1048576        // 32*16*4   = 2048 (plain stores, no zeroing)

// Output layout (float32, concatenated): boxes[32][300][4], scores[32][300],
// labels[32][300], n_valid[32]
#define OUT_SCORES  38400
#define OUT_LABELS  48000
#define OUT_NVALID  57600

// ---------------------------------------------------------------------------
// K1: single-pass filter+stage into PRIVATE per-(batch,slice) segments.
// key = (bits(v)<<32) | ~flat_idx  (desc key order == lax.top_k order:
// score desc, index asc). No global atomics, no pre-zeroing: each block
// plain-stores its own count (possibly > SEGCAP -> mega takes fallback).
__global__ __launch_bounds__(256) void stage_kernel(const float4* __restrict__ scores4,
                                                    unsigned* __restrict__ segCnt,
                                                    unsigned long long* __restrict__ candKeys) {
    __shared__ unsigned lcnt;
    int b = blockIdx.x, sl = blockIdx.y, tid = threadIdx.x;
    if (tid == 0) lcnt = 0;
    __syncthreads();
    const float4* s = scores4 + (size_t)b * NCV4 + (size_t)sl * SLICE_V4;
    unsigned long long* seg = candKeys + (size_t)b * CANDCAP + (size_t)sl * SEGCAP;
    for (int i = tid; i < SLICE_V4; i += 256) {
        float4 v = s[i];
        float c[4] = {v.x, v.y, v.z, v.w};
        unsigned flat0 = ((unsigned)sl * SLICE_V4 + (unsigned)i) * 4u;
        #pragma unroll
        for (int kc = 0; kc < 4; ++kc) {
            float x = (c[kc] > 0.001f) ? c[kc] : 0.0f;
            if (x >= STAGE_THRESH) {
                unsigned p = atomicAdd(&lcnt, 1u);
                if (p < (unsigned)SEGCAP)
                    seg[p] = ((unsigned long long)__float_as_uint(x) << 32) |
                             (unsigned long long)(0xFFFFFFFFu - (flat0 + kc));
            }
        }
    }
    __syncthreads();
    if (tid == 0) segCnt[b * NSLICE + sl] = lcnt;
}

// ---------------------------------------------------------------------------
// K2: fused per-batch sort + gather + per-class NMS + finalize. One 1024-thread
// block per batch; everything stays in LDS (~80 KB, 1 block/CU, 32 blocks).
struct PhaseA {                       // load + sort (+ exact fallback)
    unsigned long long k[CANDCAP];    // 32 KB
    unsigned fhist[NBINS];            // 16 KB (fallback only)
    unsigned scnt;
    int cut;
};
struct PhaseB {                       // gather + NMS + finalize
    float sc[TOPK];
    float oy1[TOPK], ox1[TOPK], oy2[TOPK], ox2[TOPK];  // class-offset coords
    float area[TOPK];                 // areas of offset boxes (reference order)
    float4 ob[TOPK];                  // original boxes (output)
    unsigned short cls[TOPK];
    int keep[TOPK];                   // keep flags, then in-place scan
    unsigned short wps[16][TOPK];     // per-wave: pos(10b) | sup(bit15)
    int sel[MAXDET];
};

__global__ __launch_bounds__(1024) void mega_kernel(
        const float4* __restrict__ scores4,
        const unsigned long long* __restrict__ candKeys,
        const unsigned* __restrict__ segCnt,
        const float4* __restrict__ boxes4,
        float* __restrict__ out) {
    __shared__ union { PhaseA a; PhaseB bb; } u;
    __shared__ unsigned pref[NSLICE + 1];
    __shared__ int s_fb;
    int b = blockIdx.x;
    int tid = threadIdx.x;

    // --- segment counts -> prefix sums + fast-path validity
    if (tid < NSLICE) pref[tid + 1] = segCnt[b * NSLICE + tid];
    __syncthreads();
    if (tid == 0) {
        unsigned acc = 0; int fb2 = 0;
        pref[0] = 0;
        for (int s2 = 1; s2 <= NSLICE; ++s2) {
            unsigned c2 = pref[s2];
            if (c2 > (unsigned)SEGCAP) fb2 = 1;
            acc += c2;
            pref[s2] = acc;
        }
        if (acc < (unsigned)TOPK || acc > (unsigned)CANDCAP) fb2 = 1;
        s_fb = fb2;
    }
    __syncthreads();

    unsigned M;
    if (!s_fb) {
        // --- fast path: concatenate private segments into LDS
        for (int s2 = 0; s2 < NSLICE; ++s2) {
            unsigned base2 = pref[s2], n2 = pref[s2 + 1] - base2;
            const unsigned long long* src =
                candKeys + (size_t)b * CANDCAP + (size_t)s2 * SEGCAP;
            for (unsigned t = tid; t < n2; t += 1024) u.a.k[base2 + t] = src[t];
        }
        M = pref[NSLICE];
    } else {
        // --- exact fallback: histogram -> cut -> restage (slow, correct)
        for (int i2 = tid; i2 < NBINS; i2 += 1024) u.a.fhist[i2] = 0;
        if (tid == 0) u.a.scnt = 0;
        __syncthreads();
        const float4* s = scores4 + (size_t)b * NCV4;
        for (int i2 = tid; i2 < NCV4; i2 += 1024) {
            float4 v = s[i2];
            float c4[4] = {v.x, v.y, v.z, v.w};
            #pragma unroll
            for (int kc = 0; kc < 4; ++kc) {
                float x = (c4[kc] > 0.001f) ? c4[kc] : 0.0f;
                int bin = (int)(x * 4096.0f);
                bin = bin > (NBINS - 1) ? (NBINS - 1) : bin;
                atomicAdd(&u.a.fhist[bin], 1u);
            }
        }
        __syncthreads();
        if (tid == 0) {
            unsigned acc = 0; int cb = 0;
            for (int bin = NBINS - 1; bin >= 0; --bin) {
                acc += u.a.fhist[bin];
                if (acc >= (unsigned)TOPK) { cb = bin; break; }
            }
            u.a.cut = cb;
        }
        __syncthreads();
        int cb = u.a.cut;
        for (int i2 = tid; i2 < NCV4; i2 += 1024) {
            float4 v = s[i2];
            float c4[4] = {v.x, v.y, v.z, v.w};
            unsigned flat0 = (unsigned)i2 * 4u;
            #pragma unroll
            for (int kc = 0; kc < 4; ++kc) {
                float x = (c4[kc] > 0.001f) ? c4[kc] : 0.0f;
                int bin = (int)(x * 4096.0f);
                bin = bin > (NBINS - 1) ? (NBINS - 1) : bin;
                if (bin >= cb) {
                    unsigned p = atomicAdd(&u.a.scnt, 1u);
                    if (p < (unsigned)CANDCAP)
                        u.a.k[p] = ((unsigned long long)__float_as_uint(x) << 32) |
                                   (unsigned long long)(0xFFFFFFFFu - (flat0 + kc));
                }
            }
        }
        __syncthreads();
        M = u.a.scnt;
        if (M > (unsigned)CANDCAP) M = CANDCAP;
    }
    int S = (M <= 1024u) ? 1024 : (M <= 2048u ? 2048 : CANDCAP);
    for (int i2 = tid; i2 < S; i2 += 1024)
        if (i2 >= (int)M) u.a.k[i2] = 0ull;
    __syncthreads();

    // --- bitonic sort, descending. Passes with j<=64 stay inside a
    // 128-element window owned by exactly one wave (window = compare>>6),
    // so they need no block barrier — only wave-local LDS ordering
    // (in-order DS pipe; __threadfence_block as compiler/HW insurance).
    {
        bool crossed = false;
        for (int kk = 2; kk <= S; kk <<= 1) {
            int j = kk >> 1;
            for (; j >= 128; j >>= 1) {          // cross-wave passes
                __syncthreads();
                for (int t = tid; t < S; t += 1024) {
                    int l = t ^ j;
                    if (l > t) {
                        unsigned long long a0 = u.a.k[t], c0 = u.a.k[l];
                        bool sw = ((t & kk) == 0) ? (a0 < c0) : (a0 > c0);
                        if (sw) { u.a.k[t] = c0; u.a.k[l] = a0; }
                    }
                }
                crossed = true;
            }
            if (crossed) { __syncthreads(); crossed = false; }
            int half = S >> 1;
            for (; j >= 1; j >>= 1) {            // wave-local passes (j<=64)
                for (int c2 = tid; c2 < half; c2 += 1024) {
                    int t = ((c2 & ~(j - 1)) << 1) | (c2 & (j - 1));
                    int l = t | j;
                    unsigned long long a0 = u.a.k[t], c0 = u.a.k[l];
                    bool sw = ((t & kk) == 0) ? (a0 < c0) : (a0 > c0);
                    if (sw) { u.a.k[t] = c0; u.a.k[l] = a0; }
                }
                __threadfence_block();
            }
        }
    }
    __syncthreads();

    // --- gather top-1024 into PhaseB (key read before union reuse)
    unsigned long long key = u.a.k[tid];
    __syncthreads();
    {
        float sc = __uint_as_float((unsigned)(key >> 32));
        unsigned idx = 0xFFFFFFFFu - (unsigned)(key & 0xFFFFFFFFull);
        if (idx >= (unsigned)NC) idx = 0;        // defensive (padding keys)
        unsigned bi = idx / (unsigned)C_;
        unsigned cl = idx - bi * (unsigned)C_;
        float4 bx = boxes4[(size_t)b * N_ + bi];
        float off = (float)cl * 4096.0f;         // exact
        float oy1 = bx.x + off, ox1 = bx.y + off;
        float oy2 = bx.z + off, ox2 = bx.w + off;
        u.bb.sc[tid] = sc;
        u.bb.oy1[tid] = oy1; u.bb.ox1[tid] = ox1;
        u.bb.oy2[tid] = oy2; u.bb.ox2[tid] = ox2;
        u.bb.area[tid] = __fmul_rn((ox2 - ox1) + 1.0f, (oy2 - oy1) + 1.0f);
        u.bb.ob[tid] = bx;
        u.bb.cls[tid] = (unsigned short)cl;
        u.bb.keep[tid] = 0;
    }
    __syncthreads();

    // --- per-class greedy NMS: wave w handles classes [5w, 5w+5).
    // Cross-class IoU is exactly 0 (offset gap 4096 >> max box 640), so
    // per-class greedy == reference's global sequential loop. IoU replicated
    // in f32 with __fmul_rn to block FMA contraction.
    {
        int w = tid >> 6, lane = tid & 63;
        unsigned long long lmask = (1ull << lane) - 1ull;
        unsigned short* wp = u.bb.wps[w];
        for (int cc = w * 5; cc < w * 5 + 5; ++cc) {
            int nm = 0;
            for (int chunk = 0; chunk < TOPK; chunk += 64) {
                int i2 = chunk + lane;
                bool listed = (u.bb.cls[i2] == (unsigned short)cc) &&
                              (u.bb.sc[i2] > 0.001f);
                unsigned long long mask = __ballot(listed);
                if (listed) wp[nm + __popcll(mask & lmask)] = (unsigned short)i2;
                nm += __popcll(mask);
            }
            __threadfence_block();
            int cur = 0;
            while (cur < nm) {
                int pcur = wp[cur] & 0x3FF;      // invariant: unsuppressed -> kept
                if (lane == 0) u.bb.keep[pcur] = 1;
                float cy1 = u.bb.oy1[pcur], cx1 = u.bb.ox1[pcur];
                float cy2 = u.bb.oy2[pcur], cx2 = u.bb.ox2[pcur];
                float carea = u.bb.area[pcur];
                for (int t2 = cur + 1 + lane; t2 < nm; t2 += 64) {
                    unsigned short e = wp[t2];
                    if (!(e & 0x8000)) {
                        int pj = e;
                        float yy1 = fmaxf(cy1, u.bb.oy1[pj]);
                        float xx1 = fmaxf(cx1, u.bb.ox1[pj]);
                        float yy2 = fminf(cy2, u.bb.oy2[pj]);
                        float xx2 = fminf(cx2, u.bb.ox2[pj]);
                        float w2 = fmaxf(0.0f, (xx2 - xx1) + 1.0f);
                        float h2 = fmaxf(0.0f, (yy2 - yy1) + 1.0f);
                        float inter = __fmul_rn(w2, h2);
                        float denom = (carea + u.bb.area[pj]) - inter;
                        if (inter / denom > 0.7f) wp[t2] = e | 0x8000;
                    }
                }
                __threadfence_block();
                int nxt = nm;
                for (int t2 = cur + 1 + lane; t2 < nm; t2 += 64)
                    if (!(wp[t2] & 0x8000)) { nxt = t2; break; }
                for (int o = 32; o > 0; o >>= 1) {
                    int other = __shfl_xor(nxt, o, 64);
                    nxt = nxt < other ? nxt : other;
                }
                cur = nxt;
            }
        }
    }
    __syncthreads();

    // --- finalize: stable top-300 (kept in order, then suppressed in order)
    {
        int kp = u.bb.keep[tid];
        for (int off2 = 1; off2 < TOPK; off2 <<= 1) {   // inclusive scan
            int add = (tid >= off2) ? u.bb.keep[tid - off2] : 0;
            __syncthreads();
            u.bb.keep[tid] += add;
            __syncthreads();
        }
        int nk = u.bb.keep[TOPK - 1];
        int incl = u.bb.keep[tid];
        int kexcl = incl - kp;        // exclusive kept rank
        int sexcl = tid - kexcl;      // exclusive suppressed rank
        if (kp) {
            if (kexcl < MAXDET) u.bb.sel[kexcl] = tid;
        } else {
            int slot = nk + sexcl;
            if (slot < MAXDET) u.bb.sel[slot] = tid;
        }
        __syncthreads();
        if (tid < MAXDET) {
            int p = u.bb.sel[tid];
            float sc2 = (tid < nk) ? u.bb.sc[p] : 0.0f;
            ((float4*)out)[b * MAXDET + tid] = u.bb.ob[p];
            out[OUT_SCORES + b * MAXDET + tid] = sc2;
            out[OUT_LABELS + b * MAXDET + tid] = (float)u.bb.cls[p];
        }
        if (tid == 0) out[OUT_NVALID + b] = (float)(nk < MAXDET ? nk : MAXDET);
    }
}

// ---------------------------------------------------------------------------
extern "C" void kernel_launch(void* const* d_in, const int* in_sizes, int n_in,
                              void* d_out, int out_size, void* d_ws, size_t ws_size,
                              hipStream_t stream) {
    const float* boxes  = (const float*)d_in[0];   // (32, 8400, 4)
    const float* scores = (const float*)d_in[1];   // (32, 8400, 80)
    float* out = (float*)d_out;
    char* ws = (char*)d_ws;

    unsigned long long* candKeys = (unsigned long long*)(ws + WS_CANDKEYS);
    unsigned* segCnt = (unsigned*)(ws + WS_SEGCNT);

    const float4* scores4 = (const float4*)scores;
    const float4* boxes4  = (const float4*)boxes;

    stage_kernel<<<dim3(B_, NSLICE), 256, 0, stream>>>(scores4, segCnt, candKeys);
    mega_kernel<<<B_, 1024, 0, stream>>>(scores4, candKeys, segCnt, boxes4, out);
}

// Round 6
// 198.571 us; speedup vs baseline: 1.1238x; 1.1238x over previous
//
#include <hip/hip_runtime.h>
#include <cstdint>
#include <cstddef>

// Problem constants (fixed by the reference)
#define B_      32
#define N_      8400
#define C_      80
#define NC      672000        // N_*C_
#define NCV4    168000        // NC/4
#define NBINS   4096
#define TOPK    1024
#define MAXDET  300
#define CANDCAP 4096
#define NSLICE  16
#define SLICE_V4 10500        // NCV4 / NSLICE
#define SEGCAP  256           // per-(batch,slice) key segment (expect ~82)

// Static stage threshold: score >= 4088/4096 = 0.998046875.
// Expected candidates/batch = 672000*8/4096 = 1312 (sd ~36): inside
// [TOPK, CANDCAP] with overwhelming margin. Any violating input takes the
// exact histogram fallback inside sort_gather_kernel.
#define STAGE_THRESH 0.998046875f

// Workspace layout (bytes)
#define WS_CANDKEYS  0              // 32*4096*8 = 1048576 (16 segs of 256/batch)
#define WS_SEGCNT    1048576        // 32*16*4   = 2048 (plain stores, no zeroing)
#define WS_TOPSCORE  1050624        // 32*1024*4  = 131072
#define WS_TOPBOX    1181696        // 32*1024*16 = 524288
#define WS_TOPCLS    1705984        // 32*1024*4  = 131072
#define WS_KEEP      1837056        // 32*1024*4  = 131072

// Output layout (float32, concatenated): boxes[32][300][4], scores[32][300],
// labels[32][300], n_valid[32]
#define OUT_SCORES  38400
#define OUT_LABELS  48000
#define OUT_NVALID  57600

// ---------------------------------------------------------------------------
// K1: single-pass filter+stage into PRIVATE per-(batch,slice) segments.
// key = (bits(v)<<32) | ~flat_idx  (desc key order == lax.top_k order:
// score desc, index asc). No global atomics, no pre-zeroing: each block
// plain-stores its own count (count > SEGCAP -> sort kernel takes fallback).
__global__ __launch_bounds__(256) void stage_kernel(const float4* __restrict__ scores4,
                                                    unsigned* __restrict__ segCnt,
                                                    unsigned long long* __restrict__ candKeys) {
    __shared__ unsigned lcnt;
    int b = blockIdx.x, sl = blockIdx.y, tid = threadIdx.x;
    if (tid == 0) lcnt = 0;
    __syncthreads();
    const float4* s = scores4 + (size_t)b * NCV4 + (size_t)sl * SLICE_V4;
    unsigned long long* seg = candKeys + (size_t)b * CANDCAP + (size_t)sl * SEGCAP;
    for (int i = tid; i < SLICE_V4; i += 256) {
        float4 v = s[i];
        float c[4] = {v.x, v.y, v.z, v.w};
        unsigned flat0 = ((unsigned)sl * SLICE_V4 + (unsigned)i) * 4u;
        #pragma unroll
        for (int kc = 0; kc < 4; ++kc) {
            float x = (c[kc] > 0.001f) ? c[kc] : 0.0f;
            if (x >= STAGE_THRESH) {
                unsigned p = atomicAdd(&lcnt, 1u);
                if (p < (unsigned)SEGCAP)
                    seg[p] = ((unsigned long long)__float_as_uint(x) << 32) |
                             (unsigned long long)(0xFFFFFFFFu - (flat0 + kc));
            }
        }
    }
    __syncthreads();
    if (tid == 0) segCnt[b * NSLICE + sl] = lcnt;
}

// ---------------------------------------------------------------------------
// K2: per-batch bitonic sort (descending) in LDS + gather top-1024.
// t=tid compare pattern (u64 stride-8B = 2-way bank aliasing, free on gfx950).
// Barrier-skip: passes with j<=16 are wave-local on wave64 (pair (t,t^j) and
// all its writers/readers live in one 64-aligned block handled by one wave;
// DS pipe is in-order within a wave) -> __threadfence_block only. Passes with
// j>=32 get __syncthreads (j=32 reads the prior cross-wave j=64 writes).
// Fallback (segment overflow or M out of [TOPK,CANDCAP]): exact histogram ->
// cut -> restage, self-contained per block.
__global__ __launch_bounds__(1024) void sort_gather_kernel(
        const float4* __restrict__ scores4,
        const unsigned long long* __restrict__ candKeys,
        const unsigned* __restrict__ segCnt,
        const float* __restrict__ boxes,
        float* __restrict__ topScore,
        float* __restrict__ topBox,
        int* __restrict__ topCls) {
    __shared__ union {
        unsigned long long k[CANDCAP];   // 32 KB
        unsigned fh[2 * CANDCAP];        // fallback histogram (16 KB used)
    } u;
    __shared__ unsigned pref[NSLICE + 1];
    __shared__ int s_fb;
    __shared__ unsigned scnt;
    __shared__ int s_cut;
    int b = blockIdx.x;
    int tid = threadIdx.x;

    // --- segment counts -> prefix sums + fast-path validity
    if (tid < NSLICE) pref[tid + 1] = segCnt[b * NSLICE + tid];
    __syncthreads();
    if (tid == 0) {
        unsigned acc = 0; int fb2 = 0;
        pref[0] = 0;
        for (int s2 = 1; s2 <= NSLICE; ++s2) {
            unsigned c2 = pref[s2];
            if (c2 > (unsigned)SEGCAP) fb2 = 1;
            acc += c2;
            pref[s2] = acc;
        }
        if (acc < (unsigned)TOPK || acc > (unsigned)CANDCAP) fb2 = 1;
        s_fb = fb2;
    }
    __syncthreads();

    unsigned M;
    if (!s_fb) {
        // --- fast path: concatenate private segments, one wave per segment
        int w = tid >> 6, lane = tid & 63;
        unsigned base2 = pref[w], n2 = pref[w + 1] - base2;
        const unsigned long long* src =
            candKeys + (size_t)b * CANDCAP + (size_t)w * SEGCAP;
        for (unsigned t = lane; t < n2; t += 64) u.k[base2 + t] = src[t];
        M = pref[NSLICE];
    } else {
        // --- exact fallback: histogram -> cut -> restage (slow, correct)
        for (int i2 = tid; i2 < NBINS; i2 += 1024) u.fh[i2] = 0;
        if (tid == 0) scnt = 0;
        __syncthreads();
        const float4* s = scores4 + (size_t)b * NCV4;
        for (int i2 = tid; i2 < NCV4; i2 += 1024) {
            float4 v = s[i2];
            float c4[4] = {v.x, v.y, v.z, v.w};
            #pragma unroll
            for (int kc = 0; kc < 4; ++kc) {
                float x = (c4[kc] > 0.001f) ? c4[kc] : 0.0f;
                int bin = (int)(x * 4096.0f);
                bin = bin > (NBINS - 1) ? (NBINS - 1) : bin;
                atomicAdd(&u.fh[bin], 1u);
            }
        }
        __syncthreads();
        if (tid == 0) {
            unsigned acc = 0; int cb = 0;
            for (int bin = NBINS - 1; bin >= 0; --bin) {
                acc += u.fh[bin];
                if (acc >= (unsigned)TOPK) { cb = bin; break; }
            }
            s_cut = cb;
        }
        __syncthreads();                 // fh dead after this; k may overwrite
        int cb = s_cut;
        for (int i2 = tid; i2 < NCV4; i2 += 1024) {
            float4 v = s[i2];
            float c4[4] = {v.x, v.y, v.z, v.w};
            unsigned flat0 = (unsigned)i2 * 4u;
            #pragma unroll
            for (int kc = 0; kc < 4; ++kc) {
                float x = (c4[kc] > 0.001f) ? c4[kc] : 0.0f;
                int bin = (int)(x * 4096.0f);
                bin = bin > (NBINS - 1) ? (NBINS - 1) : bin;
                if (bin >= cb) {
                    unsigned p = atomicAdd(&scnt, 1u);
                    if (p < (unsigned)CANDCAP)
                        u.k[p] = ((unsigned long long)__float_as_uint(x) << 32) |
                                 (unsigned long long)(0xFFFFFFFFu - (flat0 + kc));
                }
            }
        }
        __syncthreads();
        M = scnt;
        if (M > (unsigned)CANDCAP) M = CANDCAP;
    }
    int S = (M <= 1024u) ? 1024 : (M <= 2048u ? 2048 : CANDCAP);
    for (int i2 = tid; i2 < S; i2 += 1024)
        if (i2 >= (int)M) u.k[i2] = 0ull;
    __syncthreads();

    // --- bitonic sort, descending
    for (int kk = 2; kk <= S; kk <<= 1) {
        for (int j = kk >> 1; j > 0; j >>= 1) {
            if (j >= 32) __syncthreads();
            else         __threadfence_block();   // wave-local pass (j<=16)
            for (int t = tid; t < S; t += 1024) {
                int l = t ^ j;
                if (l > t) {
                    unsigned long long a0 = u.k[t], c0 = u.k[l];
                    bool sw = ((t & kk) == 0) ? (a0 < c0) : (a0 > c0);
                    if (sw) { u.k[t] = c0; u.k[l] = a0; }
                }
            }
        }
    }
    __syncthreads();

    // --- gather top-1024
    int i = tid;
    unsigned long long key = u.k[i];
    float sc = __uint_as_float((unsigned)(key >> 32));
    unsigned idx = 0xFFFFFFFFu - (unsigned)(key & 0xFFFFFFFFull);
    if (idx >= (unsigned)NC) idx = 0;       // defensive (padding keys)
    unsigned bi = idx / (unsigned)C_;
    unsigned cl = idx - bi * (unsigned)C_;
    const float* bp = boxes + (size_t)b * N_ * 4 + (size_t)bi * 4;
    float c0 = bp[0], c1 = bp[1], c2 = bp[2], c3 = bp[3];
    topScore[b * TOPK + i] = sc;
    float* tb = topBox + ((size_t)b * TOPK + i) * 4;
    tb[0] = c0; tb[1] = c1; tb[2] = c2; tb[3] = c3;
    topCls[b * TOPK + i] = (int)cl;
}

// ---------------------------------------------------------------------------
// K3: per-(batch,class) greedy NMS, one 64-thread block per (b,c).
// Cross-class IoU is exactly 0 (offset gap 4096 >> max box 640), so per-class
// greedy NMS is exactly equivalent to the reference's global sequential loop.
// Ballot-compaction preserves score order; wave-parallel suppression.
// IoU replicated in f32 with __fmul_rn to block FMA contraction.
#define CLS_CAP 256
__global__ __launch_bounds__(64) void nms_kernel(const float* __restrict__ topScore,
                                                 const float* __restrict__ topBox,
                                                 const int* __restrict__ topCls,
                                                 int* __restrict__ keep) {
    __shared__ unsigned short pos[CLS_CAP];
    __shared__ float by1[CLS_CAP], bx1[CLS_CAP], by2[CLS_CAP], bx2[CLS_CAP];
    __shared__ float barea[CLS_CAP];
    __shared__ unsigned char sup[CLS_CAP];
    int b = blockIdx.x;
    int c = blockIdx.y;
    int lane = threadIdx.x;
    const float* ts = topScore + b * TOPK;
    const int*   tc = topCls + b * TOPK;
    int*         kp = keep + b * TOPK;
    float off = (float)c * 4096.0f;         // exact
    int base = 0;
    for (int chunkS = 0; chunkS < TOPK; chunkS += 64) {
        int i = chunkS + lane;
        int cls = tc[i];
        float sc = ts[i];
        bool mine = (cls == c);
        bool listed = mine && (sc > 0.001f);
        if (mine) kp[i] = 0;                 // default; kept ones overwritten below
        unsigned long long mask = __ballot(listed);
        int rank = __popcll(mask & ((1ull << lane) - 1ull));
        if (listed) {
            int slot = base + rank;
            if (slot < CLS_CAP) {
                pos[slot] = (unsigned short)i;
                const float* tb = topBox + ((size_t)(b * TOPK + i)) * 4;
                float y1 = tb[0] + off, x1 = tb[1] + off;
                float y2 = tb[2] + off, x2 = tb[3] + off;
                by1[slot] = y1; bx1[slot] = x1; by2[slot] = y2; bx2[slot] = x2;
                barea[slot] = __fmul_rn((x2 - x1) + 1.0f, (y2 - y1) + 1.0f);
                sup[slot] = 0;
            }
        }
        base += __popcll(mask);
    }
    int m = base < CLS_CAP ? base : CLS_CAP;
    __syncthreads();
    int cur = 0;
    while (cur < m) {
        // invariant: slot `cur` is unsuppressed -> kept
        if (lane == 0) kp[pos[cur]] = 1;
        float cy1 = by1[cur], cx1 = bx1[cur], cy2 = by2[cur], cx2 = bx2[cur];
        float carea = barea[cur];
        for (int j = cur + 1 + lane; j < m; j += 64) {
            if (!sup[j]) {
                float yy1 = fmaxf(cy1, by1[j]), xx1 = fmaxf(cx1, bx1[j]);
                float yy2 = fminf(cy2, by2[j]), xx2 = fminf(cx2, bx2[j]);
                float w = fmaxf(0.0f, (xx2 - xx1) + 1.0f);
                float h = fmaxf(0.0f, (yy2 - yy1) + 1.0f);
                float inter = __fmul_rn(w, h);
                float denom = (carea + barea[j]) - inter;
                float iou = inter / denom;
                if (iou > 0.7f) sup[j] = 1;
            }
        }
        __syncthreads();
        int nxt = m;
        for (int j = cur + 1 + lane; j < m; j += 64)
            if (!sup[j]) { nxt = j; break; }
        for (int o = 32; o > 0; o >>= 1) {
            int other = __shfl_xor(nxt, o, 64);
            nxt = nxt < other ? nxt : other;
        }
        cur = nxt;
    }
}

// ---------------------------------------------------------------------------
// K4: stable top-300 of final_scores: kept positions in order, then suppressed
// positions in order (score-0 ties break by lower index). Write all outputs.
__global__ __launch_bounds__(1024) void finalize_kernel(const float* __restrict__ topScore,
                                                        const float* __restrict__ topBox,
                                                        const int* __restrict__ topCls,
                                                        const int* __restrict__ keep,
                                                        float* __restrict__ out) {
    __shared__ int sk[TOPK];
    __shared__ int sel[MAXDET];
    int b = blockIdx.x;
    int i = threadIdx.x;
    int kp = keep[b * TOPK + i];
    sk[i] = kp;
    __syncthreads();
    // inclusive Hillis-Steele scan over 1024
    for (int off = 1; off < TOPK; off <<= 1) {
        int add = (i >= off) ? sk[i - off] : 0;
        __syncthreads();
        sk[i] += add;
        __syncthreads();
    }
    int nk = sk[TOPK - 1];
    int incl = sk[i];
    int kexcl = incl - kp;       // exclusive kept rank
    int sexcl = i - kexcl;       // exclusive suppressed rank
    if (kp) {
        if (kexcl < MAXDET) sel[kexcl] = i;
    } else {
        int slot = nk + sexcl;
        if (slot < MAXDET) sel[slot] = i;
    }
    __syncthreads();
    if (i < MAXDET) {
        int p = sel[i];
        float sc = (i < nk) ? topScore[b * TOPK + p] : 0.0f;
        const float* tb = topBox + ((size_t)b * TOPK + p) * 4;
        float* ob = out + ((size_t)b * MAXDET + i) * 4;
        ob[0] = tb[0]; ob[1] = tb[1]; ob[2] = tb[2]; ob[3] = tb[3];
        out[OUT_SCORES + b * MAXDET + i] = sc;
        out[OUT_LABELS + b * MAXDET + i] = (float)topCls[b * TOPK + p];
    }
    if (i == 0) out[OUT_NVALID + b] = (float)(nk < MAXDET ? nk : MAXDET);
}

// ---------------------------------------------------------------------------
extern "C" void kernel_launch(void* const* d_in, const int* in_sizes, int n_in,
                              void* d_out, int out_size, void* d_ws, size_t ws_size,
                              hipStream_t stream) {
    const float* boxes  = (const float*)d_in[0];   // (32, 8400, 4)
    const float* scores = (const float*)d_in[1];   // (32, 8400, 80)
    float* out = (float*)d_out;
    char* ws = (char*)d_ws;

    unsigned long long* candKeys = (unsigned long long*)(ws + WS_CANDKEYS);
    unsigned* segCnt = (unsigned*)(ws + WS_SEGCNT);
    float* topScore = (float*)(ws + WS_TOPSCORE);
    float* topBox = (float*)(ws + WS_TOPBOX);
    int* topCls = (int*)(ws + WS_TOPCLS);
    int* keep = (int*)(ws + WS_KEEP);

    const float4* scores4 = (const float4*)scores;

    stage_kernel<<<dim3(B_, NSLICE), 256, 0, stream>>>(scores4, segCnt, candKeys);
    sort_gather_kernel<<<B_, 1024, 0, stream>>>(scores4, candKeys, segCnt, boxes,
                                                topScore, topBox, topCls);
    nms_kernel<<<dim3(B_, C_), 64, 0, stream>>>(topScore, topBox, topCls, keep);
    finalize_kernel<<<B_, 1024, 0, stream>>>(topScore, topBox, topCls, keep, out);
}

// Round 7
// 190.499 us; speedup vs baseline: 1.1715x; 1.0424x over previous
//
#include <hip/hip_runtime.h>
#include <cstdint>
#include <cstddef>

// Problem constants (fixed by the reference)
#define B_      32
#define N_      8400
#define C_      80
#define NC      672000        // N_*C_
#define NCV4    168000        // NC/4
#define NBINS   4096
#define TOPK    1024
#define MAXDET  300
#define CANDCAP 4096
#define NSLICE  16
#define SLICE_V4 10500        // NCV4 / NSLICE
#define NBKT    8             // score bins 4088..4095 (all x in [0.998..1))
#define SEGB    64            // per-(batch,bucket,slice) cap (mean 10.25, 17 sigma)
#define BSORT   256           // per-bucket sort size (mean 164, 7.2 sigma)

// Static stage threshold: score >= 4088/4096 = 0.998046875.
// Expected candidates/batch = 672000*8/4096 = 1312 (sd ~36). Bucket = bin-4088
// partitions candidates into 8 ORDER-DISJOINT groups (floor is monotone, float
// bits are monotone): sorted buckets concatenated 7..0 == exact lax.top_k
// order (score desc, index asc via key low bits). Violating inputs take the
// exact histogram fallback (fbFlag-gated).
#define STAGE_THRESH 0.998046875f

// Workspace layout (bytes)
#define WS_SEGKEYS  0           // 32*8*16*64*8 = 2097152
#define WS_SEGCNT   2097152     // 32*8*16*4    = 16384
#define WS_FBFLAG   2113536     // 32*4         = 128
#define WS_TOPSCORE 2113664     // 32*1024*4    = 131072
#define WS_TOPBOX   2244736     // 32*1024*16   = 524288
#define WS_TOPCLS   2769024     // 32*1024*4    = 131072
#define WS_KEEP     2900096     // 32*1024*4    = 131072

// Output layout (float32, concatenated): boxes[32][300][4], scores[32][300],
// labels[32][300], n_valid[32]
#define OUT_SCORES  38400
#define OUT_LABELS  48000
#define OUT_NVALID  57600

// ---------------------------------------------------------------------------
// K1: single-pass filter+stage into PRIVATE per-(batch,bucket,slice) segments.
// key = (bits(v)<<32) | ~flat_idx. 8 LDS counters per block; plain global
// stores; no global atomics, no pre-zeroing (raw counts let sortb detect
// overflow -> fallback).
__global__ __launch_bounds__(256) void stage_kernel(const float4* __restrict__ scores4,
                                                    unsigned* __restrict__ segCnt,
                                                    unsigned long long* __restrict__ segKeys) {
    __shared__ unsigned lcnt[NBKT];
    int b = blockIdx.x, sl = blockIdx.y, tid = threadIdx.x;
    if (tid < NBKT) lcnt[tid] = 0;
    __syncthreads();
    const float4* s = scores4 + (size_t)b * NCV4 + (size_t)sl * SLICE_V4;
    for (int i = tid; i < SLICE_V4; i += 256) {
        float4 v = s[i];
        float c[4] = {v.x, v.y, v.z, v.w};
        unsigned flat0 = ((unsigned)sl * SLICE_V4 + (unsigned)i) * 4u;
        #pragma unroll
        for (int kc = 0; kc < 4; ++kc) {
            float x = (c[kc] > 0.001f) ? c[kc] : 0.0f;
            if (x >= STAGE_THRESH) {
                int bin = (int)(x * 4096.0f);             // exact: x * 2^12
                bin = bin > (NBINS - 1) ? (NBINS - 1) : bin;
                int bkt = bin - 4088;                      // 0..7
                unsigned p = atomicAdd(&lcnt[bkt], 1u);
                if (p < (unsigned)SEGB)
                    segKeys[(((size_t)(b * NBKT + bkt)) * NSLICE + sl) * SEGB + p] =
                        ((unsigned long long)__float_as_uint(x) << 32) |
                        (unsigned long long)(0xFFFFFFFFu - (flat0 + kc));
            }
        }
    }
    __syncthreads();
    if (tid < NBKT) segCnt[(b * NBKT + tid) * NSLICE + sl] = lcnt[tid];
}

// ---------------------------------------------------------------------------
// K2: one WAVE per (batch,bucket) — 256 parallel blocks. Loads its bucket
// (<=256 keys), barrier-free single-wave bitonic sort (lockstep; DS in-order
// within a wave; __threadfence_block stops compiler caching), computes global
// base = sum of higher buckets, writes topScore/topBox/topCls directly for
// ranks < 1024. Validity computed identically by all 8 blocks of a batch;
// bkt-0 block publishes fbFlag.
__global__ __launch_bounds__(64) void sortb_kernel(
        const unsigned long long* __restrict__ segKeys,
        const unsigned* __restrict__ segCnt,
        const float4* __restrict__ boxes4,
        unsigned* __restrict__ fbFlag,
        float* __restrict__ topScore,
        float4* __restrict__ topBox4,
        int* __restrict__ topCls) {
    __shared__ unsigned long long k[BSORT];
    __shared__ unsigned bsum[NBKT];
    __shared__ unsigned bok[NBKT];
    __shared__ unsigned spref[NSLICE + 1];
    int b = blockIdx.x, bkt = blockIdx.y, lane = threadIdx.x;

    // per-bucket totals + per-segment cap check (whole batch, all lanes agree)
    if (lane < NBKT) {
        const unsigned* c = segCnt + (b * NBKT + lane) * NSLICE;
        unsigned ssum = 0, ok = 1;
        for (int sl = 0; sl < NSLICE; ++sl) {
            unsigned v = c[sl];
            if (v > (unsigned)SEGB) ok = 0;
            ssum += v;
        }
        bsum[lane] = ssum; bok[lane] = ok;
    }
    __threadfence_block();
    unsigned M = 0, base = 0; int valid = 1;
    #pragma unroll
    for (int t = 0; t < NBKT; ++t) {
        unsigned s2 = bsum[t];
        if (!bok[t] || s2 > (unsigned)BSORT) valid = 0;
        M += s2;
        if (t > bkt) base += s2;
    }
    unsigned n = bsum[bkt];
    if (M < (unsigned)TOPK || M > (unsigned)CANDCAP) valid = 0;
    if (bkt == 0 && lane == 0) fbFlag[b] = valid ? 0u : 1u;
    if (!valid || base >= (unsigned)TOPK || n == 0) return;

    // concatenate this bucket's 16 slice-segments into LDS
    if (lane == 0) {
        unsigned acc = 0; spref[0] = 0;
        const unsigned* c = segCnt + (b * NBKT + bkt) * NSLICE;
        for (int sl = 0; sl < NSLICE; ++sl) { acc += c[sl]; spref[sl + 1] = acc; }
    }
    __threadfence_block();
    for (int sl = 0; sl < NSLICE; ++sl) {
        unsigned b0 = spref[sl], c2 = spref[sl + 1] - b0;
        const unsigned long long* src =
            segKeys + (((size_t)(b * NBKT + bkt)) * NSLICE + sl) * SEGB;
        for (unsigned t = lane; t < c2; t += 64) k[b0 + t] = src[t];
    }
    for (unsigned t = n + lane; t < (unsigned)BSORT; t += 64) k[t] = 0ull;
    __threadfence_block();

    // single-wave bitonic sort, descending — no barriers needed
    for (int kk = 2; kk <= BSORT; kk <<= 1) {
        for (int j = kk >> 1; j > 0; j >>= 1) {
            for (int c2 = lane; c2 < BSORT / 2; c2 += 64) {
                int t = ((c2 & ~(j - 1)) << 1) | (c2 & (j - 1));
                int l = t | j;
                unsigned long long a0 = k[t], c0 = k[l];
                bool sw = ((t & kk) == 0) ? (a0 < c0) : (a0 > c0);
                if (sw) { k[t] = c0; k[l] = a0; }
            }
            __threadfence_block();
        }
    }

    // write ranks [0, min(n, 1024-base)) at global positions base+r
    unsigned wlim = (unsigned)TOPK - base; if (wlim > n) wlim = n;
    for (unsigned r = lane; r < wlim; r += 64) {
        unsigned long long key = k[r];
        float sc = __uint_as_float((unsigned)(key >> 32));
        unsigned idx = 0xFFFFFFFFu - (unsigned)(key & 0xFFFFFFFFull);
        if (idx >= (unsigned)NC) idx = 0;    // defensive
        unsigned bi = idx / (unsigned)C_;
        unsigned cl = idx - bi * (unsigned)C_;
        unsigned pos = base + r;
        topScore[b * TOPK + pos] = sc;
        topBox4[b * TOPK + pos] = boxes4[(size_t)b * N_ + bi];
        topCls[b * TOPK + pos] = (int)cl;
    }
}

// ---------------------------------------------------------------------------
// K3: gated exact fallback (histogram -> cut -> restage -> full bitonic ->
// gather). Early-exits when fbFlag[b]==0 (the common case): ~1 read per block.
__global__ __launch_bounds__(1024) void fallback_kernel(
        const float4* __restrict__ scores4,
        const unsigned* __restrict__ fbFlag,
        const float* __restrict__ boxes,
        float* __restrict__ topScore,
        float* __restrict__ topBox,
        int* __restrict__ topCls) {
    int b = blockIdx.x;
    if (fbFlag[b] == 0) return;          // uniform: safe before barriers
    __shared__ union {
        unsigned long long k[CANDCAP];   // 32 KB
        unsigned fh[NBINS];              // first 16 KB (dead before k written)
    } u;
    __shared__ unsigned scnt;
    __shared__ int s_cut;
    int tid = threadIdx.x;
    for (int i2 = tid; i2 < NBINS; i2 += 1024) u.fh[i2] = 0;
    if (tid == 0) scnt = 0;
    __syncthreads();
    const float4* s = scores4 + (size_t)b * NCV4;
    for (int i2 = tid; i2 < NCV4; i2 += 1024) {
        float4 v = s[i2];
        float c4[4] = {v.x, v.y, v.z, v.w};
        #pragma unroll
        for (int kc = 0; kc < 4; ++kc) {
            float x = (c4[kc] > 0.001f) ? c4[kc] : 0.0f;
            int bin = (int)(x * 4096.0f);
            bin = bin > (NBINS - 1) ? (NBINS - 1) : bin;
            atomicAdd(&u.fh[bin], 1u);
        }
    }
    __syncthreads();
    if (tid == 0) {
        unsigned acc = 0; int cb = 0;
        for (int bin = NBINS - 1; bin >= 0; --bin) {
            acc += u.fh[bin];
            if (acc >= (unsigned)TOPK) { cb = bin; break; }
        }
        s_cut = cb;
    }
    __syncthreads();                     // fh dead after this; k may overwrite
    int cb = s_cut;
    for (int i2 = tid; i2 < NCV4; i2 += 1024) {
        float4 v = s[i2];
        float c4[4] = {v.x, v.y, v.z, v.w};
        unsigned flat0 = (unsigned)i2 * 4u;
        #pragma unroll
        for (int kc = 0; kc < 4; ++kc) {
            float x = (c4[kc] > 0.001f) ? c4[kc] : 0.0f;
            int bin = (int)(x * 4096.0f);
            bin = bin > (NBINS - 1) ? (NBINS - 1) : bin;
            if (bin >= cb) {
                unsigned p = atomicAdd(&scnt, 1u);
                if (p < (unsigned)CANDCAP)
                    u.k[p] = ((unsigned long long)__float_as_uint(x) << 32) |
                             (unsigned long long)(0xFFFFFFFFu - (flat0 + kc));
            }
        }
    }
    __syncthreads();
    unsigned M = scnt; if (M > (unsigned)CANDCAP) M = CANDCAP;
    int S = (M <= 1024u) ? 1024 : (M <= 2048u ? 2048 : CANDCAP);
    for (int i2 = tid; i2 < S; i2 += 1024)
        if (i2 >= (int)M) u.k[i2] = 0ull;
    __syncthreads();
    for (int kk = 2; kk <= S; kk <<= 1) {
        for (int j = kk >> 1; j > 0; j >>= 1) {
            for (int t = tid; t < S; t += 1024) {
                int l = t ^ j;
                if (l > t) {
                    unsigned long long a0 = u.k[t], c0 = u.k[l];
                    bool sw = ((t & kk) == 0) ? (a0 < c0) : (a0 > c0);
                    if (sw) { u.k[t] = c0; u.k[l] = a0; }
                }
            }
            __syncthreads();
        }
    }
    unsigned long long key = u.k[tid];
    float sc = __uint_as_float((unsigned)(key >> 32));
    unsigned idx = 0xFFFFFFFFu - (unsigned)(key & 0xFFFFFFFFull);
    if (idx >= (unsigned)NC) idx = 0;
    unsigned bi = idx / (unsigned)C_;
    unsigned cl = idx - bi * (unsigned)C_;
    const float* bp = boxes + (size_t)b * N_ * 4 + (size_t)bi * 4;
    float c0 = bp[0], c1 = bp[1], c2 = bp[2], c3 = bp[3];
    topScore[b * TOPK + tid] = sc;
    float* tb = topBox + ((size_t)b * TOPK + tid) * 4;
    tb[0] = c0; tb[1] = c1; tb[2] = c2; tb[3] = c3;
    topCls[b * TOPK + tid] = (int)cl;
}

// ---------------------------------------------------------------------------
// K4: per-(batch,class) greedy NMS, one 64-thread block per (b,c).
// Cross-class IoU is exactly 0 (offset gap 4096 >> max box 640), so per-class
// greedy NMS is exactly equivalent to the reference's global sequential loop.
// IoU replicated in f32 with __fmul_rn to block FMA contraction.
#define CLS_CAP 256
__global__ __launch_bounds__(64) void nms_kernel(const float* __restrict__ topScore,
                                                 const float* __restrict__ topBox,
                                                 const int* __restrict__ topCls,
                                                 int* __restrict__ keep) {
    __shared__ unsigned short pos[CLS_CAP];
    __shared__ float by1[CLS_CAP], bx1[CLS_CAP], by2[CLS_CAP], bx2[CLS_CAP];
    __shared__ float barea[CLS_CAP];
    __shared__ unsigned char sup[CLS_CAP];
    int b = blockIdx.x;
    int c = blockIdx.y;
    int lane = threadIdx.x;
    const float* ts = topScore + b * TOPK;
    const int*   tc = topCls + b * TOPK;
    int*         kp = keep + b * TOPK;
    float off = (float)c * 4096.0f;         // exact
    int base = 0;
    for (int chunkS = 0; chunkS < TOPK; chunkS += 64) {
        int i = chunkS + lane;
        int cls = tc[i];
        float sc = ts[i];
        bool mine = (cls == c);
        bool listed = mine && (sc > 0.001f);
        if (mine) kp[i] = 0;                 // default; kept ones overwritten below
        unsigned long long mask = __ballot(listed);
        int rank = __popcll(mask & ((1ull << lane) - 1ull));
        if (listed) {
            int slot = base + rank;
            if (slot < CLS_CAP) {
                pos[slot] = (unsigned short)i;
                const float* tb = topBox + ((size_t)(b * TOPK + i)) * 4;
                float y1 = tb[0] + off, x1 = tb[1] + off;
                float y2 = tb[2] + off, x2 = tb[3] + off;
                by1[slot] = y1; bx1[slot] = x1; by2[slot] = y2; bx2[slot] = x2;
                barea[slot] = __fmul_rn((x2 - x1) + 1.0f, (y2 - y1) + 1.0f);
                sup[slot] = 0;
            }
        }
        base += __popcll(mask);
    }
    int m = base < CLS_CAP ? base : CLS_CAP;
    __syncthreads();
    int cur = 0;
    while (cur < m) {
        // invariant: slot `cur` is unsuppressed -> kept
        if (lane == 0) kp[pos[cur]] = 1;
        float cy1 = by1[cur], cx1 = bx1[cur], cy2 = by2[cur], cx2 = bx2[cur];
        float carea = barea[cur];
        for (int j = cur + 1 + lane; j < m; j += 64) {
            if (!sup[j]) {
                float yy1 = fmaxf(cy1, by1[j]), xx1 = fmaxf(cx1, bx1[j]);
                float yy2 = fminf(cy2, by2[j]), xx2 = fminf(cx2, bx2[j]);
                float w = fmaxf(0.0f, (xx2 - xx1) + 1.0f);
                float h = fmaxf(0.0f, (yy2 - yy1) + 1.0f);
                float inter = __fmul_rn(w, h);
                float denom = (carea + barea[j]) - inter;
                float iou = inter / denom;
                if (iou > 0.7f) sup[j] = 1;
            }
        }
        __syncthreads();
        int nxt = m;
        for (int j = cur + 1 + lane; j < m; j += 64)
            if (!sup[j]) { nxt = j; break; }
        for (int o = 32; o > 0; o >>= 1) {
            int other = __shfl_xor(nxt, o, 64);
            nxt = nxt < other ? nxt : other;
        }
        cur = nxt;
    }
}

// ---------------------------------------------------------------------------
// K5: stable top-300 of final_scores: kept positions in order, then suppressed
// positions in order (score-0 ties break by lower index). Write all outputs.
__global__ __launch_bounds__(1024) void finalize_kernel(const float* __restrict__ topScore,
                                                        const float* __restrict__ topBox,
                                                        const int* __restrict__ topCls,
                                                        const int* __restrict__ keep,
                                                        float* __restrict__ out) {
    __shared__ int sk[TOPK];
    __shared__ int sel[MAXDET];
    int b = blockIdx.x;
    int i = threadIdx.x;
    int kp = keep[b * TOPK + i];
    sk[i] = kp;
    __syncthreads();
    // inclusive Hillis-Steele scan over 1024
    for (int off = 1; off < TOPK; off <<= 1) {
        int add = (i >= off) ? sk[i - off] : 0;
        __syncthreads();
        sk[i] += add;
        __syncthreads();
    }
    int nk = sk[TOPK - 1];
    int incl = sk[i];
    int kexcl = incl - kp;       // exclusive kept rank
    int sexcl = i - kexcl;       // exclusive suppressed rank
    if (kp) {
        if (kexcl < MAXDET) sel[kexcl] = i;
    } else {
        int slot = nk + sexcl;
        if (slot < MAXDET) sel[slot] = i;
    }
    __syncthreads();
    if (i < MAXDET) {
        int p = sel[i];
        float sc = (i < nk) ? topScore[b * TOPK + p] : 0.0f;
        const float* tb = topBox + ((size_t)b * TOPK + p) * 4;
        float* ob = out + ((size_t)b * MAXDET + i) * 4;
        ob[0] = tb[0]; ob[1] = tb[1]; ob[2] = tb[2]; ob[3] = tb[3];
        out[OUT_SCORES + b * MAXDET + i] = sc;
        out[OUT_LABELS + b * MAXDET + i] = (float)topCls[b * TOPK + p];
    }
    if (i == 0) out[OUT_NVALID + b] = (float)(nk < MAXDET ? nk : MAXDET);
}

// ---------------------------------------------------------------------------
extern "C" void kernel_launch(void* const* d_in, const int* in_sizes, int n_in,
                              void* d_out, int out_size, void* d_ws, size_t ws_size,
                              hipStream_t stream) {
    const float* boxes  = (const float*)d_in[0];   // (32, 8400, 4)
    const float* scores = (const float*)d_in[1];   // (32, 8400, 80)
    float* out = (float*)d_out;
    char* ws = (char*)d_ws;

    unsigned long long* segKeys = (unsigned long long*)(ws + WS_SEGKEYS);
    unsigned* segCnt = (unsigned*)(ws + WS_SEGCNT);
    unsigned* fbFlag = (unsigned*)(ws + WS_FBFLAG);
    float* topScore = (float*)(ws + WS_TOPSCORE);
    float* topBox = (float*)(ws + WS_TOPBOX);
    int* topCls = (int*)(ws + WS_TOPCLS);
    int* keep = (int*)(ws + WS_KEEP);

    const float4* scores4 = (const float4*)scores;
    const float4* boxes4  = (const float4*)boxes;

    stage_kernel<<<dim3(B_, NSLICE), 256, 0, stream>>>(scores4, segCnt, segKeys);
    sortb_kernel<<<dim3(B_, NBKT), 64, 0, stream>>>(segKeys, segCnt, boxes4, fbFlag,
                                                    topScore, (float4*)topBox, topCls);
    fallback_kernel<<<B_, 1024, 0, stream>>>(scores4, fbFlag, boxes,
                                             topScore, topBox, topCls);
    nms_kernel<<<dim3(B_, C_), 64, 0, stream>>>(topScore, topBox, topCls, keep);
    finalize_kernel<<<B_, 1024, 0, stream>>>(topScore, topBox, topCls, keep, out);
}